// Round 1
// baseline (4724.701 us; speedup 1.0000x reference)
//
#include <hip/hip_runtime.h>

#define NN 50000
#define NE 10000
#define NNZC 200000
#define OBSD 128
#define LATD 256
#define NSTEPS 8

typedef unsigned short u16;
typedef __attribute__((ext_vector_type(8))) short bf16x8;
typedef __attribute__((ext_vector_type(4))) float f32x4;
typedef __attribute__((ext_vector_type(4))) u16 us4;

__device__ __forceinline__ u16 f2b(float f) {
  unsigned int u = __builtin_bit_cast(unsigned int, f);
  u = (u + 0x7FFFu + ((u >> 16) & 1u)) >> 16;
  return (u16)u;
}
__device__ __forceinline__ float b2f(u16 h) {
  unsigned int u = ((unsigned int)h) << 16;
  return __builtin_bit_cast(float, u);
}
__device__ __forceinline__ float fast_tanh(float x) {
  float e = __expf(2.0f * x);
  return 1.0f - 2.0f / (e + 1.0f);
}

typedef __attribute__((address_space(1))) const unsigned int GU32;
typedef __attribute__((address_space(3))) unsigned int LU32;
__device__ __forceinline__ void async16(const void* g, void* l) {
  __builtin_amdgcn_global_load_lds((GU32*)g, (LU32*)l, 16, 0, 0);
}

// ---------------- CSR build ----------------

__global__ void count_kernel(const int* __restrict__ ni, const int* __restrict__ ei,
                             int* __restrict__ cnt_n, int* __restrict__ cnt_e, int nnz) {
  int i = blockIdx.x * blockDim.x + threadIdx.x;
  if (i < nnz) {
    atomicAdd(&cnt_n[ni[i]], 1);
    atomicAdd(&cnt_e[ei[i]], 1);
  }
}

__global__ __launch_bounds__(1024) void scan_kernel(const int* __restrict__ cnt,
                                                    int* __restrict__ off, int* __restrict__ cur,
                                                    float* __restrict__ recip, int n) {
  __shared__ int sm[1024];
  const int tid = threadIdx.x;
  int base = 0;
  const int nchunk = (n + 1023) >> 10;
  for (int c = 0; c < nchunk; ++c) {
    int i = (c << 10) + tid;
    int v = (i < n) ? cnt[i] : 0;
    sm[tid] = v;
    __syncthreads();
    for (int s = 1; s < 1024; s <<= 1) {
      int tv = (tid >= s) ? sm[tid - s] : 0;
      __syncthreads();
      sm[tid] += tv;
      __syncthreads();
    }
    int incl = sm[tid];
    if (i < n) {
      int ex = base + incl - v;
      off[i] = ex;
      cur[i] = ex;
      recip[i] = 1.0f / fmaxf((float)v, 1.0f);
    }
    int tot = sm[1023];
    __syncthreads();
    base += tot;
  }
  if (tid == 0) off[n] = base;
}

__global__ void fill_kernel(const int* __restrict__ ni, const int* __restrict__ ei,
                            int* __restrict__ cur_n, int* __restrict__ cur_e,
                            int* __restrict__ lst_n, int* __restrict__ lst_e, int nnz) {
  int i = blockIdx.x * blockDim.x + threadIdx.x;
  if (i < nnz) {
    int n = ni[i], e = ei[i];
    lst_e[atomicAdd(&cur_e[e], 1)] = n;  // per-edge list of nodes
    lst_n[atomicAdd(&cur_n[n], 1)] = e;  // per-node list of edges
  }
}

// ---------------- small prep ----------------

// W [K x N] f32 row-major -> WT [N x K] bf16
__global__ void transpose_kernel(const float* __restrict__ W, u16* __restrict__ WT, int K, int N) {
  int i = blockIdx.x * blockDim.x + threadIdx.x;
  if (i >= K * N) return;
  int k = i / N, n = i - k * N;
  WT[n * K + k] = f2b(W[i]);
}

__global__ void to_bf16_kernel(const float* __restrict__ src, u16* __restrict__ dst, int n) {
  int i = (blockIdx.x * blockDim.x + threadIdx.x) * 4;
  if (i >= n) return;
  float4 v = *reinterpret_cast<const float4*>(src + i);
  us4 o;
  o.x = f2b(v.x); o.y = f2b(v.y); o.z = f2b(v.z); o.w = f2b(v.w);
  *reinterpret_cast<us4*>(dst + i) = o;
}

// ---------------- segment mean (one wave per segment) ----------------

template <typename SrcT>
__global__ __launch_bounds__(256) void agg_kernel(const SrcT* __restrict__ src,
                                                  const int* __restrict__ off,
                                                  const int* __restrict__ lst,
                                                  const float* __restrict__ recip,
                                                  u16* __restrict__ dst, int nseg) {
  const int lane = threadIdx.x & 63;
  const int seg = (blockIdx.x << 2) + (threadIdx.x >> 6);
  if (seg >= nseg) return;
  const int s = off[seg], e = off[seg + 1];
  float a0 = 0.f, a1 = 0.f, a2 = 0.f, a3 = 0.f;
  for (int p = s; p < e; ++p) {
    int r = lst[p];
    if constexpr (sizeof(SrcT) == 4) {
      float4 v = *(reinterpret_cast<const float4*>(src + (size_t)r * LATD) + lane);
      a0 += v.x; a1 += v.y; a2 += v.z; a3 += v.w;
    } else {
      us4 v = *(reinterpret_cast<const us4*>(src + (size_t)r * LATD) + lane);
      a0 += b2f(v.x); a1 += b2f(v.y); a2 += b2f(v.z); a3 += b2f(v.w);
    }
  }
  const float rc = recip[seg];
  us4 o;
  o.x = f2b(a0 * rc); o.y = f2b(a1 * rc); o.z = f2b(a2 * rc); o.w = f2b(a3 * rc);
  *(reinterpret_cast<us4*>(dst + (size_t)seg * LATD) + lane) = o;
}

// ---------------- MFMA GEMM: C = A[MxK](bf16) * BT[NxK]^T(bf16) + bias ----------------

enum { EPI_RELU_BF16, EPI_BF16, EPI_F32, EPI_K1, EPI_K2, EPI_K3, EPI_K4 };

template <int MODE>
__global__ __launch_bounds__(256) void gemm_kernel(
    const u16* __restrict__ A, const u16* __restrict__ BT, const float* __restrict__ bias,
    int M, int N, int K,
    u16* __restrict__ outb, float* __restrict__ outf,
    float* __restrict__ zbuf, float* __restrict__ accbuf, u16* __restrict__ ztb, float czt) {
  __shared__ u16 lA[128 * 32];
  __shared__ u16 lB[128 * 32];
  const int t = threadIdx.x;
  const int m0 = blockIdx.x * 128, n0 = blockIdx.y * 128;
  const int srow = t >> 2;
  const int gslot = (t & 3) ^ ((srow >> 1) & 3);  // XOR swizzle: 16B slot within 64B row-chunk

  int ar0 = m0 + srow;      if (ar0 > M - 1) ar0 = M - 1;
  int ar1 = m0 + srow + 64; if (ar1 > M - 1) ar1 = M - 1;
  const u16* gA0 = A + (size_t)ar0 * K + gslot * 8;
  const u16* gA1 = A + (size_t)ar1 * K + gslot * 8;
  const u16* gB0 = BT + (size_t)(n0 + srow) * K + gslot * 8;
  const u16* gB1 = BT + (size_t)(n0 + srow + 64) * K + gslot * 8;
  char* lAd0 = (char*)lA + t * 16; char* lAd1 = lAd0 + 4096;
  char* lBd0 = (char*)lB + t * 16; char* lBd1 = lBd0 + 4096;

  const int lane = t & 63, wid = t >> 6;
  const int wm = wid >> 1, wn = wid & 1;
  const int lrow = lane & 15, kg = lane >> 4;

  f32x4 acc[4][4] = {};
  const char* lAb = (const char*)lA;
  const char* lBb = (const char*)lB;

  for (int kk = 0; kk < K; kk += 32) {
    async16(gA0 + kk, lAd0);
    async16(gA1 + kk, lAd1);
    async16(gB0 + kk, lBd0);
    async16(gB1 + kk, lBd1);
    __syncthreads();
    bf16x8 af[4], bg[4];
#pragma unroll
    for (int i = 0; i < 4; ++i) {
      int rA = wm * 64 + i * 16 + lrow;
      af[i] = *(const bf16x8*)(lAb + rA * 64 + (((kg ^ (rA >> 1)) & 3) << 4));
      int rB = wn * 64 + i * 16 + lrow;
      bg[i] = *(const bf16x8*)(lBb + rB * 64 + (((kg ^ (rB >> 1)) & 3) << 4));
    }
#pragma unroll
    for (int i = 0; i < 4; ++i)
#pragma unroll
      for (int j = 0; j < 4; ++j)
        acc[i][j] = __builtin_amdgcn_mfma_f32_16x16x32_bf16(af[i], bg[j], acc[i][j], 0, 0, 0);
    __syncthreads();
  }

  const float dt6 = 0.125f / 6.0f;
#pragma unroll
  for (int ti = 0; ti < 4; ++ti) {
    const int grb = m0 + wm * 64 + ti * 16 + (kg << 2);
#pragma unroll
    for (int tj = 0; tj < 4; ++tj) {
      const int gc = n0 + wn * 64 + tj * 16 + lrow;
      const float bv = bias[gc];
#pragma unroll
      for (int j = 0; j < 4; ++j) {
        const int gr = grb + j;
        if (gr >= M) continue;
        float v = acc[ti][tj][j] + bv;
        const size_t idx = (size_t)gr * N + gc;
        if constexpr (MODE == EPI_RELU_BF16) {
          outb[idx] = f2b(fmaxf(v, 0.0f));
        } else if constexpr (MODE == EPI_BF16) {
          outb[idx] = f2b(v);
        } else if constexpr (MODE == EPI_F32) {
          outf[idx] = v;
        } else if constexpr (MODE == EPI_K1) {
          float kv = fast_tanh(v);
          accbuf[idx] = kv;
          ztb[idx] = f2b(zbuf[idx] + czt * kv);
        } else if constexpr (MODE == EPI_K2 || MODE == EPI_K3) {
          float kv = fast_tanh(v);
          accbuf[idx] += 2.0f * kv;
          ztb[idx] = f2b(zbuf[idx] + czt * kv);
        } else {  // EPI_K4
          float kv = fast_tanh(v);
          zbuf[idx] = zbuf[idx] + dt6 * (accbuf[idx] + kv);
        }
      }
    }
  }
}

// ---------------- launch ----------------

extern "C" void kernel_launch(void* const* d_in, const int* in_sizes, int n_in,
                              void* d_out, int out_size, void* d_ws, size_t ws_size,
                              hipStream_t stream) {
  const float* X = (const float*)d_in[0];
  const float* encW0 = (const float*)d_in[1];
  const float* encb0 = (const float*)d_in[2];
  const float* encW1 = (const float*)d_in[3];
  const float* encb1 = (const float*)d_in[4];
  const float* Wne = (const float*)d_in[5];
  const float* bne = (const float*)d_in[6];
  const float* Wen = (const float*)d_in[7];
  const float* ben = (const float*)d_in[8];
  const float* decW0 = (const float*)d_in[9];
  const float* decb0 = (const float*)d_in[10];
  const float* decW1 = (const float*)d_in[11];
  const float* decb1 = (const float*)d_in[12];
  const int* node_idx = (const int*)d_in[13];
  const int* edge_idx = (const int*)d_in[14];
  float* out = (float*)d_out;

  char* p = (char*)d_ws;
  auto alloc = [&](size_t bytes) {
    char* r = p;
    p += (bytes + 255) & ~(size_t)255;
    return r;
  };
  float* z      = (float*)alloc((size_t)NN * LATD * 4);
  float* accb   = (float*)alloc((size_t)NN * LATD * 4);
  u16* zt       = (u16*)alloc((size_t)NN * LATD * 2);   // bf16 temp state / X / z-bf16
  u16* mh       = (u16*)alloc((size_t)NN * LATD * 2);   // m / h1 / d1
  u16* eagg     = (u16*)alloc((size_t)NE * LATD * 2);
  u16* et       = (u16*)alloc((size_t)NE * LATD * 2);
  u16* encW0T   = (u16*)alloc((size_t)OBSD * LATD * 2);
  u16* encW1T   = (u16*)alloc((size_t)LATD * LATD * 2);
  u16* WneT     = (u16*)alloc((size_t)LATD * LATD * 2);
  u16* WenT     = (u16*)alloc((size_t)LATD * LATD * 2);
  u16* decW0T   = (u16*)alloc((size_t)LATD * LATD * 2);
  u16* decW1T   = (u16*)alloc((size_t)LATD * OBSD * 2);
  int* cnt      = (int*)alloc((size_t)(NE + NN) * 4);
  int* cnt_e = cnt; int* cnt_n = cnt + NE;
  int* off_e    = (int*)alloc((size_t)(NE + 1) * 4);
  int* off_n    = (int*)alloc((size_t)(NN + 1) * 4);
  int* cur_e    = (int*)alloc((size_t)NE * 4);
  int* cur_n    = (int*)alloc((size_t)NN * 4);
  int* lst_e    = (int*)alloc((size_t)NNZC * 4);
  int* lst_n    = (int*)alloc((size_t)NNZC * 4);
  float* recip_e = (float*)alloc((size_t)NE * 4);
  float* recip_n = (float*)alloc((size_t)NN * 4);

  size_t needed = (size_t)(p - (char*)d_ws);
  if (needed > ws_size) {
    // unambiguous sentinel: absmax ~3.4e38 means "workspace too small"
    hipMemsetAsync(d_out, 0x7F, (size_t)out_size * 4, stream);
    return;
  }

  // CSR build
  hipMemsetAsync(cnt, 0, (size_t)(NE + NN) * 4, stream);
  count_kernel<<<(NNZC + 255) / 256, 256, 0, stream>>>(node_idx, edge_idx, cnt_n, cnt_e, NNZC);
  scan_kernel<<<1, 1024, 0, stream>>>(cnt_e, off_e, cur_e, recip_e, NE);
  scan_kernel<<<1, 1024, 0, stream>>>(cnt_n, off_n, cur_n, recip_n, NN);
  fill_kernel<<<(NNZC + 255) / 256, 256, 0, stream>>>(node_idx, edge_idx, cur_n, cur_e, lst_n, lst_e, NNZC);

  // weight prep (transpose + bf16)
  transpose_kernel<<<(OBSD * LATD + 255) / 256, 256, 0, stream>>>(encW0, encW0T, OBSD, LATD);
  transpose_kernel<<<(LATD * LATD + 255) / 256, 256, 0, stream>>>(encW1, encW1T, LATD, LATD);
  transpose_kernel<<<(LATD * LATD + 255) / 256, 256, 0, stream>>>(Wne, WneT, LATD, LATD);
  transpose_kernel<<<(LATD * LATD + 255) / 256, 256, 0, stream>>>(Wen, WenT, LATD, LATD);
  transpose_kernel<<<(LATD * LATD + 255) / 256, 256, 0, stream>>>(decW0, decW0T, LATD, LATD);
  transpose_kernel<<<(LATD * OBSD + 255) / 256, 256, 0, stream>>>(decW1, decW1T, LATD, OBSD);

  const dim3 blk(256);
  const dim3 g50((NN + 127) / 128, LATD / 128);   // (391, 2)
  const dim3 g10((NE + 127) / 128, LATD / 128);   // (79, 2)
  const dim3 gdec((NN + 127) / 128, OBSD / 128);  // (391, 1)

  // encode: h1 = relu(X@W0+b0) ; z = h1@W1+b1 (f32)
  to_bf16_kernel<<<(NN * OBSD / 4 + 255) / 256, 256, 0, stream>>>(X, zt, NN * OBSD);
  gemm_kernel<EPI_RELU_BF16><<<g50, blk, 0, stream>>>(zt, encW0T, encb0, NN, LATD, OBSD,
                                                      mh, nullptr, nullptr, nullptr, nullptr, 0.f);
  gemm_kernel<EPI_F32><<<g50, blk, 0, stream>>>(mh, encW1T, encb1, NN, LATD, LATD,
                                                nullptr, z, nullptr, nullptr, nullptr, 0.f);

  // RK4 steps
  for (int s = 0; s < NSTEPS; ++s) {
    for (int k = 0; k < 4; ++k) {
      if (k == 0)
        agg_kernel<float><<<(NE + 3) / 4, blk, 0, stream>>>((const float*)z, off_e, lst_e, recip_e, eagg, NE);
      else
        agg_kernel<u16><<<(NE + 3) / 4, blk, 0, stream>>>(zt, off_e, lst_e, recip_e, eagg, NE);
      gemm_kernel<EPI_BF16><<<g10, blk, 0, stream>>>(eagg, WneT, bne, NE, LATD, LATD,
                                                     et, nullptr, nullptr, nullptr, nullptr, 0.f);
      agg_kernel<u16><<<(NN + 3) / 4, blk, 0, stream>>>(et, off_n, lst_n, recip_n, mh, NN);
      if (k == 0)
        gemm_kernel<EPI_K1><<<g50, blk, 0, stream>>>(mh, WenT, ben, NN, LATD, LATD,
                                                     nullptr, nullptr, z, accb, zt, 0.0625f);
      else if (k == 1)
        gemm_kernel<EPI_K2><<<g50, blk, 0, stream>>>(mh, WenT, ben, NN, LATD, LATD,
                                                     nullptr, nullptr, z, accb, zt, 0.0625f);
      else if (k == 2)
        gemm_kernel<EPI_K3><<<g50, blk, 0, stream>>>(mh, WenT, ben, NN, LATD, LATD,
                                                     nullptr, nullptr, z, accb, zt, 0.125f);
      else
        gemm_kernel<EPI_K4><<<g50, blk, 0, stream>>>(mh, WenT, ben, NN, LATD, LATD,
                                                     nullptr, nullptr, z, accb, zt, 0.f);
    }
  }

  // decode: d1 = relu(z@dW0+db0) ; out = d1@dW1+db1
  to_bf16_kernel<<<(NN * LATD / 4 + 255) / 256, 256, 0, stream>>>(z, zt, NN * LATD);
  gemm_kernel<EPI_RELU_BF16><<<g50, blk, 0, stream>>>(zt, decW0T, decb0, NN, LATD, LATD,
                                                      mh, nullptr, nullptr, nullptr, nullptr, 0.f);
  gemm_kernel<EPI_F32><<<gdec, blk, 0, stream>>>(mh, decW1T, decb1, NN, OBSD, LATD,
                                                 nullptr, out, nullptr, nullptr, nullptr, 0.f);
}